// Round 11
// baseline (273.471 us; speedup 1.0000x reference)
//
#include <hip/hip_runtime.h>

typedef unsigned short u16;
typedef __attribute__((ext_vector_type(4))) float f32x4;
typedef __attribute__((ext_vector_type(8))) short bf16x8;
typedef __attribute__((ext_vector_type(4))) short s16x4;

#define MFMA_BF16(a, b, c) __builtin_amdgcn_mfma_f32_16x16x32_bf16((a), (b), (c), 0, 0, 0)

// K=16 bf16 MFMA (2-VGPR operands). Its A-operand layout (A[i=lane&15][k=4g+j])
// exactly matches swapped-QK^T's C/D layout -> P feeds PV with ZERO shuffles.
#if defined(__has_builtin)
#if __has_builtin(__builtin_amdgcn_mfma_f32_16x16x16bf16_1k)
#define HAVE_MFMA16 1
#define MFMA16(a, b, c) __builtin_amdgcn_mfma_f32_16x16x16bf16_1k((a), (b), (c), 0, 0, 0)
#endif
#endif
#ifndef HAVE_MFMA16
#define HAVE_MFMA16 0
#endif

static constexpr int kDim   = 1024;
static constexpr int kSeq   = 2048;
static constexpr int kBatch = 4;
static constexpr int kHeads = 16;
static constexpr int kTok   = kBatch * kSeq;   // 8192
static constexpr int kQKV   = 3 * kDim;        // 3072 (fused QKV width)
// Softmax in log2 domain: S2 = (q.k) * dim^-0.5 * log2(e); scale folded into Q
// at the QKV-GEMM epilogue so attention does NO per-score multiply.
static constexpr float kQscale = 0.045084220027780106f;  // 0.03125 * log2(e)

__device__ __forceinline__ u16 f2bf(float f) {
  unsigned int u = __float_as_uint(f);
  u += 0x7fffu + ((u >> 16) & 1u);   // round-nearest-even
  return (u16)(u >> 16);
}

__device__ __forceinline__ float fast_exp2(float x) {
#if __has_builtin(__builtin_amdgcn_exp2f)
  return __builtin_amdgcn_exp2f(x);
#else
  return exp2f(x);
#endif
}

// pack two f32 -> (bf16(hi)<<16)|bf16(lo), round-half-up
__device__ __forceinline__ unsigned pack_bf16(float lo, float hi) {
  const unsigned ulo = __float_as_uint(lo) + 0x8000u;
  const unsigned uhi = __float_as_uint(hi) + 0x8000u;
#if __has_builtin(__builtin_amdgcn_perm)
  return __builtin_amdgcn_perm(uhi, ulo, 0x07060302u);
#else
  return (uhi & 0xFFFF0000u) | (ulo >> 16);
#endif
}

__device__ __forceinline__ void gl_lds16(const void* g, void* l) {
  __builtin_amdgcn_global_load_lds(
      (const __attribute__((address_space(1))) void*)g,
      (__attribute__((address_space(3))) void*)l, 16, 0, 0);
}

// ---------------- fused prep: x->bf16 + all three weight transposes ----------------
// One dispatch replaces 4 (saves 3 inter-dispatch bubbles).
// blocks [0,4096): cvt x; [4096,4352): Wq^T; [4352,4864): Wkv^T; [4864,5120): Wout^T
__global__ __launch_bounds__(256) void prep(const float* __restrict__ x,
                                            const float* __restrict__ Wq,
                                            const float* __restrict__ Wkv,
                                            const float* __restrict__ Wout,
                                            u16* __restrict__ xb,
                                            u16* __restrict__ Wqkvt,
                                            u16* __restrict__ Wot) {
  const int bid = blockIdx.x;
  const int t = threadIdx.x;
  if (bid < 4096) {  // ---- cvt: 8 f32 -> 8 bf16 per thread ----
    const int i = bid * 256 + t;
    const float4* p = (const float4*)x + (size_t)i * 2;
    float4 a = p[0], c = p[1];
    alignas(16) u16 o[8];
    o[0] = f2bf(a.x); o[1] = f2bf(a.y); o[2] = f2bf(a.z); o[3] = f2bf(a.w);
    o[4] = f2bf(c.x); o[5] = f2bf(c.y); o[6] = f2bf(c.z); o[7] = f2bf(c.w);
    *(uint4*)(xb + (size_t)i * 8) = *(const uint4*)o;
    return;
  }
  // ---- transpose+convert one 64x64 tile: src f32 [R=1024][C] -> dst bf16 [C][1024] ----
  __shared__ u16 tile[64][65];
  const float* src;
  u16* dst;
  int C, bx, by;
  if (bid < 4352)      { const int id = bid - 4096; src = Wq;   dst = Wqkvt;                          C = kDim;     bx = id & 15; by = id >> 4; }
  else if (bid < 4864) { const int id = bid - 4352; src = Wkv;  dst = Wqkvt + (size_t)kDim * kDim;    C = 2 * kDim; bx = id & 31; by = id >> 5; }
  else                 { const int id = bid - 4864; src = Wout; dst = Wot;                            C = kDim;     bx = id & 15; by = id >> 4; }
  const int r0 = by * 64, c0 = bx * 64;
#pragma unroll
  for (int i = 0; i < 16; ++i) {
    const int idx = i * 256 + t;
    const int rr = idx >> 6, cc = idx & 63;
    tile[rr][cc] = f2bf(src[(size_t)(r0 + rr) * C + c0 + cc]);
  }
  __syncthreads();
#pragma unroll
  for (int i = 0; i < 16; ++i) {
    const int idx = i * 256 + t;
    const int rr = idx >> 6, cc = idx & 63;
    dst[(size_t)(c0 + rr) * kDim + r0 + cc] = tile[cc][rr];
  }
}

// ---------------- V transpose: QKV bf16 [8192][3072] (v at col 2048+) -> Vt [bh][64 d][2048 n] ----------------
__global__ __launch_bounds__(256) void transpose_v(const u16* __restrict__ QKV,
                                                   u16* __restrict__ Vt) {
  __shared__ u16 tile[64][65];
  const int n0 = blockIdx.x * 64;
  const int bh = blockIdx.y;
  const int b = bh >> 4, h = bh & 15;
  const int t = threadIdx.x;
#pragma unroll
  for (int i = 0; i < 16; ++i) {
    const int idx = i * 256 + t;
    const int nn = idx >> 6, dd = idx & 63;
    tile[nn][dd] = QKV[(size_t)(b * kSeq + n0 + nn) * kQKV + 2048 + h * 64 + dd];
  }
  __syncthreads();
#pragma unroll
  for (int i = 0; i < 16; ++i) {
    const int idx = i * 256 + t;
    const int dd = idx >> 6, nn = idx & 63;
    Vt[((size_t)bh * 64 + dd) * kSeq + n0 + nn] = tile[nn][dd];
  }
}

// ---------------- GEMM: C[M,N] = A[M,K] @ Bt[N,K]^T  (bf16 in, fp32 acc) ----------------
// m97-derived: 128x128 tile, BK=64, 4 waves (2x2), global_load_lds width 16,
// T2 granule swizzle, T1 XCD-chunked block swizzle. (unchanged from round 9/10)
template <int OUT_F32>
__global__ __launch_bounds__(256) void gemm_bt(const u16* __restrict__ A,
                                               const u16* __restrict__ Bt,
                                               void* __restrict__ Cout,
                                               const float* __restrict__ bias,
                                               int M, int N, int K,
                                               int qcols, float qs) {
  __shared__ u16 As[128 * 64];   // [row][64 cols], granule-swizzled, 16 KB
  __shared__ u16 Bs[128 * 64];
  const int t = threadIdx.x;
  const int l = t & 63, w = t >> 6;
  const int g = l >> 4, r = l & 15;

  const int gx = gridDim.x;
  int wg = blockIdx.y * gx + blockIdx.x;
  const int chunk = (gx * gridDim.y) >> 3;
  wg = (wg & 7) * chunk + (wg >> 3);
  const int m0 = (wg / gx) * 128, n0 = (wg % gx) * 128;
  const int wr = (w >> 1) * 64, wc = (w & 1) * 64;

  f32x4 acc[4][4];
#pragma unroll
  for (int m = 0; m < 4; ++m)
#pragma unroll
    for (int n = 0; n < 4; ++n) acc[m][n] = f32x4{0.f, 0.f, 0.f, 0.f};

  const int srow = t >> 3;
  const int sgran = t & 7;
  const int scol = (sgran ^ (srow & 7)) * 8;
  const u16* ga = A + (size_t)(m0 + srow) * K + scol;
  const u16* gb = Bt + (size_t)(n0 + srow) * K + scol;
  char* lA = (char*)As + t * 16;
  char* lB = (char*)Bs + t * 16;
  const int rsw = r & 7;  // read-side swizzle key

  for (int k0 = 0; k0 < K; k0 += 64) {
#pragma unroll
    for (int i = 0; i < 4; ++i) {
      gl_lds16(ga + k0 + (size_t)(i * 32) * K, lA + i * 4096);
      gl_lds16(gb + k0 + (size_t)(i * 32) * K, lB + i * 4096);
    }
    __syncthreads();
#pragma unroll
    for (int kk = 0; kk < 2; ++kk) {
      bf16x8 af[4], bfr[4];
#pragma unroll
      for (int m = 0; m < 4; ++m)
        af[m] = *(const bf16x8*)(As + (wr + m * 16 + r) * 64 + (((kk * 4 + g) ^ rsw) * 8));
#pragma unroll
      for (int n = 0; n < 4; ++n)
        bfr[n] = *(const bf16x8*)(Bs + (wc + n * 16 + r) * 64 + (((kk * 4 + g) ^ rsw) * 8));
#pragma unroll
      for (int m = 0; m < 4; ++m)
#pragma unroll
        for (int n = 0; n < 4; ++n)
          acc[m][n] = MFMA_BF16(af[m], bfr[n], acc[m][n]);
    }
    __syncthreads();
  }

#pragma unroll
  for (int m = 0; m < 4; ++m)
#pragma unroll
    for (int n = 0; n < 4; ++n)
#pragma unroll
      for (int j = 0; j < 4; ++j) {
        // C/D layout: col = lane&15, row = (lane>>4)*4 + j   [m89]
        const int row = m0 + wr + m * 16 + g * 4 + j;
        const int col = n0 + wc + n * 16 + r;
        if (OUT_F32) {
          ((float*)Cout)[(size_t)row * N + col] = acc[m][n][j] + bias[col];
        } else {
          float v = acc[m][n][j];
          if (col < qcols) v *= qs;
          ((u16*)Cout)[(size_t)row * N + col] = f2bf(v);
        }
      }
}

// ---------------- causal flash attention ----------------
// QBLK=128, 4 waves x 32 q-rows (u=0,1 sub-tiles of 16): each shared K/V LDS
// read now feeds TWO MFMA -> LDS bytes per q-row HALVED (round-10 counters
// showed attn is LDS-pipe-bound: 8 waves x 16KB/tile/CU).
// Swapped QK^T (S^T = mfma(K,Q)); exp2 softmax, scale pre-folded into Q.
// T2 both-sides LDS swizzle; T1 XCD swizzle; double-buffered K/V + counted
// vmcnt(4) (4 gl_lds16/thread/tile at 256 threads). PV via K=16 MFMA (P in-reg).
__global__ __launch_bounds__(256, 2) void attn_fwd(const u16* __restrict__ QKV,
                                                   const u16* __restrict__ Vt,
                                                   u16* __restrict__ Ob) {
  __shared__ u16 Kl[2][64 * 64];  // [kv][d], granule-swizzled, 8 KB each
  __shared__ u16 Vl[2][64 * 64];  // [d][kv], granule-swizzled
  // grid is (8, 64) = 512 blocks; chunk = 64
  int wg = blockIdx.y * 8 + blockIdx.x;
  wg = (wg & 7) * 64 + (wg >> 3);
  const int ib = wg & 7;       // 0..7  (causal pair index)
  const int bh = wg >> 3;      // 0..63
  const int b = bh >> 4, h = bh & 15;
  const int t = threadIdx.x;
  const int w = t >> 6;            // 0..3
  const int l = t & 63;
  const int g = l >> 4;
  const int qr = l & 15;
  const int sw = qr & 7;           // read-side swizzle key (row&7 == qr&7)
  const int srow = t >> 3;         // staging row (0..31)
  const int sgran = t & 7;         // LDS granule this thread's 16B lands in
  const int sg_off = (sgran ^ (srow & 7)) * 8;  // pre-swizzled SOURCE granule
  // rows srow and srow+32 share (row&7) -> same swizzle key for both halves.

  const u16* kbase = QKV + (size_t)b * kSeq * kQKV + 1024 + h * 64 + (size_t)srow * kQKV + sg_off;
  const u16* vbase = Vt + ((size_t)bh * 64 + srow) * kSeq + sg_off;

  for (int pass = 0; pass < 2; ++pass) {
    const int qblk = pass ? (15 - ib) : ib;
    const int q0 = qblk * 128;
    const int wrow = q0 + w * 32;          // wave's first q-row
    const int qrow0 = wrow + qr;           // u=0 softmax row for this lane
    const int qrow1 = wrow + 16 + qr;      // u=1

    // Q fragments (B-operand of swapped QK^T), two 16-row sub-tiles
    bf16x8 qf[2][2];
#pragma unroll
    for (int u = 0; u < 2; ++u) {
      const u16* qptr = QKV + (size_t)(b * kSeq + wrow + u * 16 + qr) * kQKV + h * 64 + g * 8;
      qf[u][0] = *(const bf16x8*)qptr;
      qf[u][1] = *(const bf16x8*)(qptr + 32);
    }

    f32x4 oacc[2][4];
#pragma unroll
    for (int u = 0; u < 2; ++u)
#pragma unroll
      for (int d = 0; d < 4; ++d) oacc[u][d] = f32x4{0.f, 0.f, 0.f, 0.f};
    float lsum0 = 0.f, lsum1 = 0.f;

    const int nkv = 2 * qblk + 2;  // causal: kv-tiles up to the diagonal

    // prologue: stage tile 0 into buf 0 (4 ops: K lo/hi rows, V lo/hi rows)
    gl_lds16(kbase, (char*)Kl[0] + t * 16);
    gl_lds16(kbase + (size_t)32 * kQKV, (char*)Kl[0] + 4096 + t * 16);
    gl_lds16(vbase, (char*)Vl[0] + t * 16);
    gl_lds16(vbase + (size_t)32 * kSeq, (char*)Vl[0] + 4096 + t * 16);

    for (int kb = 0; kb < nkv; ++kb) {
      const int cur = kb & 1;
      // issue next tile's stage BEFORE waiting (overlap with this tile's compute)
      if (kb + 1 < nkv) {
        const int kv1 = (kb + 1) * 64;
        gl_lds16(kbase + (size_t)kv1 * kQKV, (char*)Kl[cur ^ 1] + t * 16);
        gl_lds16(kbase + (size_t)(kv1 + 32) * kQKV, (char*)Kl[cur ^ 1] + 4096 + t * 16);
        gl_lds16(vbase + kv1, (char*)Vl[cur ^ 1] + t * 16);
        gl_lds16(vbase + (size_t)32 * kSeq + kv1, (char*)Vl[cur ^ 1] + 4096 + t * 16);
        asm volatile("s_waitcnt vmcnt(4)" ::: "memory");  // tile kb landed; kb+1 in flight
      } else {
        asm volatile("s_waitcnt vmcnt(0)" ::: "memory");
      }
      __builtin_amdgcn_s_barrier();     // all waves' stage of tile kb landed
      __builtin_amdgcn_sched_barrier(0);

      const u16* Kc = Kl[cur];
      const u16* Vc = Vl[cur];
      const int kv0 = kb * 64;
      // wave-level causal classification (wave rows: wrow .. wrow+31)
      const bool any_valid = kv0 <= wrow + 31;        // else fully masked
      const bool need_mask = kv0 + 63 > wrow;         // some lane straddles

      if (any_valid) {
        // S^T tiles: sacc[u][n] rows = kv local n*16 + g*4 + j, col = q-row qr
        f32x4 sacc[2][4];
#pragma unroll
        for (int u = 0; u < 2; ++u)
#pragma unroll
          for (int n = 0; n < 4; ++n) sacc[u][n] = f32x4{0.f, 0.f, 0.f, 0.f};
        __builtin_amdgcn_s_setprio(1);
#pragma unroll
        for (int n = 0; n < 4; ++n)
#pragma unroll
          for (int c = 0; c < 2; ++c) {
            // ONE K-fragment read feeds BOTH q-sub-tiles
            bf16x8 kf = *(const bf16x8*)(Kc + (n * 16 + qr) * 64 + ((c * 4 + g) ^ sw) * 8);
            sacc[0][n] = MFMA_BF16(kf, qf[0][c], sacc[0][n]);
            sacc[1][n] = MFMA_BF16(kf, qf[1][c], sacc[1][n]);
          }
        __builtin_amdgcn_s_setprio(0);

        // p = exp2(s) (clamped), mask inline, accumulate denominator, pack bf16
        unsigned pk[2][4][2];
#pragma unroll
        for (int n = 0; n < 4; ++n)
#pragma unroll
          for (int hw = 0; hw < 2; ++hw) {
            const int kvb = kv0 + n * 16 + g * 4 + hw * 2;
#pragma unroll
            for (int u = 0; u < 2; ++u) {
              const int qrow_u = u ? qrow1 : qrow0;
              float s0 = sacc[u][n][hw * 2];
              float s1 = sacc[u][n][hw * 2 + 1];
              if (need_mask) {
                if (kvb > qrow_u) s0 = -30000.0f;
                if (kvb + 1 > qrow_u) s1 = -30000.0f;
              }
              const float p0 = fast_exp2(fminf(s0, 60.f));
              const float p1 = fast_exp2(fminf(s1, 60.f));
              if (u) lsum1 += p0 + p1; else lsum0 += p0 + p1;
              pk[u][n][hw] = pack_bf16(p0, p1);
            }
          }

#if HAVE_MFMA16
        // PV via K=16 MFMA: lane already holds A[q=qr][k=4g+j] = P[qr][kv0+16n+4g+j].
        // ONE V-fragment read feeds BOTH q-sub-tiles.
        __builtin_amdgcn_s_setprio(1);
#pragma unroll
        for (int n = 0; n < 4; ++n) {
          union { unsigned uu[2]; s16x4 v; } pa0, pa1;
          pa0.uu[0] = pk[0][n][0]; pa0.uu[1] = pk[0][n][1];
          pa1.uu[0] = pk[1][n][0]; pa1.uu[1] = pk[1][n][1];
#pragma unroll
          for (int d = 0; d < 4; ++d) {
            const s16x4 vb = *(const s16x4*)(Vc + (d * 16 + qr) * 64 +
                                             (((2 * n + (g >> 1)) ^ sw) << 3) +
                                             ((g & 1) << 2));
            oacc[0][d] = MFMA16(pa0.v, vb, oacc[0][d]);
            oacc[1][d] = MFMA16(pa1.v, vb, oacc[1][d]);
          }
        }
        __builtin_amdgcn_s_setprio(0);
#else
        // Fallback: redistribute P^T -> PV A-fragments via register shuffles.
        const int src0 = qr | (((g << 1) & 3) << 4);
        const int src1 = qr | ((((g << 1) + 1) & 3) << 4);
        const bool hi = (g >> 1) != 0;
#pragma unroll
        for (int u = 0; u < 2; ++u)
#pragma unroll
          for (int c = 0; c < 2; ++c) {
            const unsigned a0 = __shfl(pk[u][2 * c][0], src0);
            const unsigned a1 = __shfl(pk[u][2 * c][1], src0);
            const unsigned a2 = __shfl(pk[u][2 * c + 1][0], src0);
            const unsigned a3 = __shfl(pk[u][2 * c + 1][1], src0);
            const unsigned b0 = __shfl(pk[u][2 * c][0], src1);
            const unsigned b1 = __shfl(pk[u][2 * c][1], src1);
            const unsigned b2 = __shfl(pk[u][2 * c + 1][0], src1);
            const unsigned b3 = __shfl(pk[u][2 * c + 1][1], src1);
            union { unsigned uu[4]; bf16x8 v; } af;
            af.uu[0] = hi ? a2 : a0;
            af.uu[1] = hi ? a3 : a1;
            af.uu[2] = hi ? b2 : b0;
            af.uu[3] = hi ? b3 : b1;
#pragma unroll
            for (int d = 0; d < 4; ++d) {
              bf16x8 vf = *(const bf16x8*)(Vc + (d * 16 + qr) * 64 + ((c * 4 + g) ^ sw) * 8);
              oacc[u][d] = MFMA_BF16(af.v, vf, oacc[u][d]);
            }
          }
#endif
      }
      // all waves done reading buf[cur] before anyone overwrites it next iter
      __builtin_amdgcn_s_barrier();
    }

    // denominator reduce + normalize + store, per q-sub-tile
#pragma unroll
    for (int u = 0; u < 2; ++u) {
      float ls = u ? lsum1 : lsum0;
      ls += __shfl_xor(ls, 16);
      ls += __shfl_xor(ls, 32);
      const float invl = 1.0f / ls;
      float ir[4];
#pragma unroll
      for (int j = 0; j < 4; ++j) ir[j] = __shfl(invl, (l & 48) | (g * 4 + j));
#pragma unroll
      for (int d = 0; d < 4; ++d)
#pragma unroll
        for (int j = 0; j < 4; ++j) {
          const int row = wrow + u * 16 + g * 4 + j;
          const int col = h * 64 + d * 16 + qr;
          Ob[(size_t)(b * kSeq + row) * kDim + col] = f2bf(oacc[u][d][j] * ir[j]);
        }
    }
    // pass-2 prologue stage is safe: all threads passed the final s_barrier
  }
}

// ---------------- launcher ----------------
extern "C" void kernel_launch(void* const* d_in, const int* in_sizes, int n_in,
                              void* d_out, int out_size, void* d_ws, size_t ws_size,
                              hipStream_t stream) {
  const float* x    = (const float*)d_in[0];
  const float* Wq   = (const float*)d_in[1];
  const float* Wkv  = (const float*)d_in[2];
  const float* Wout = (const float*)d_in[3];
  const float* bout = (const float*)d_in[4];
  float* out = (float*)d_out;

  char* p = (char*)d_ws;
  u16* xb    = (u16*)p; p += (size_t)kTok * kDim * 2;       // 16 MB
  u16* Wqkvt = (u16*)p; p += (size_t)kQKV * kDim * 2;       //  6 MB  [3072][1024]
  u16* Wot   = (u16*)p; p += (size_t)kDim * kDim * 2;       //  2 MB
  u16* QKV   = (u16*)p; p += (size_t)kTok * kQKV * 2;       // 48 MB  [8192][3072]
  u16* Vt    = (u16*)p; p += (size_t)64 * 64 * kSeq * 2;    // 16 MB
  u16* Ob    = (u16*)p; p += (size_t)kTok * kDim * 2;       // 16 MB  (total ~104 MB)

  // one fused prep dispatch: cvt(4096) + Wq^T(256) + Wkv^T(512) + Wout^T(256)
  prep<<<dim3(5120), 256, 0, stream>>>(x, Wq, Wkv, Wout, xb, Wqkvt, Wot);

  gemm_bt<0><<<dim3(kQKV / 128, kTok / 128), 256, 0, stream>>>(
      xb, Wqkvt, QKV, nullptr, kTok, kQKV, kDim, kDim, kQscale);
  transpose_v<<<dim3(kSeq / 64, kBatch * kHeads), 256, 0, stream>>>(QKV, Vt);
  attn_fwd<<<dim3(kSeq / 256, kBatch * kHeads), 256, 0, stream>>>(QKV, Vt, Ob);
  gemm_bt<1><<<dim3(kDim / 128, kTok / 128), 256, 0, stream>>>(
      Ob, Wot, out, bout, kTok, kDim, kDim, 0, 1.0f);
}